// Round 2
// baseline (114.636 us; speedup 1.0000x reference)
//
#include <hip/hip_runtime.h>

#define IMG_H 1080
#define IMG_W 1920
#define TILE_W 128
#define TILE_H 32
#define SW 134           // TILE_W + 6
#define SH 38            // TILE_H + 6
#define SP 136           // padded LDS row stride (floats); 136*4B = 16B multiple

// Nonzero iff the 16-bit circular mask has 9 consecutive set bits.
// (Reference's 24-bit buffer test == circular run-of-9; final &0xFFFF dropped:
//  bits 16..23 are duplicate windows, bits 24+ are zeroed by the x>>8 AND.)
__device__ __forceinline__ unsigned det9(unsigned m) {
    unsigned x = m | (m << 16);
    unsigned t = x & (x >> 1);   // run 2
    t &= t >> 2;                 // run 4
    t &= t >> 4;                 // run 8
    t &= x >> 8;                 // run 9
    return t;
}

__device__ __forceinline__ float elem(const float4& v, int k) {
    switch (k & 3) {
        case 0: return v.x;
        case 1: return v.y;
        case 2: return v.z;
        default: return v.w;
    }
}

__global__ __launch_bounds__(256, 4) void fast_score_kernel(const float* __restrict__ img,
                                                            float* __restrict__ out) {
    __shared__ float sm[SH * SP];

    const int n  = blockIdx.z;
    const int x0 = blockIdx.x * TILE_W;
    const int y0 = blockIdx.y * TILE_H;
    const int tid = threadIdx.x;

    const float* in = img + (size_t)n * (IMG_H * IMG_W);
    float* op = out + (size_t)n * (IMG_H * IMG_W);

    // ---- stage tile + halo into LDS (replicate-clamped) ----
    {
        const int lane = tid & 63;
        const int rgrp = tid >> 6;
        for (int r = rgrp; r < SH; r += 4) {
            int gy = y0 - 3 + r;
            gy = min(max(gy, 0), IMG_H - 1);
            const float* rowp = in + (size_t)gy * IMG_W;
            for (int c = lane; c < SW; c += 64) {
                int gx = x0 - 3 + c;
                gx = min(max(gx, 0), IMG_W - 1);
                sm[r * SP + c] = rowp[gx];
            }
        }
    }
    __syncthreads();

    // ---- 4x4 output patch per thread, rolling 7-row register window ----
    const int cg = tid & 31;     // 32 col groups * 4 = 128 cols
    const int rg = tid >> 5;     // 8 row groups * 4 = 32 rows
    const int C = cg * 4;        // tile-local first output col
    const int R = rg * 4;        // tile-local first output row

    constexpr int DY[16] = {0, 1, 2, 3, 3, 3, 2, 1, 0, -1, -2, -3, -3, -3, -2, -1};
    constexpr int DX[16] = {-3, -3, -2, -1, 0, 1, 2, 3, 3, 3, 2, 1, 0, -1, -2, -3};

    float4 w[7][3];   // circular row buffer: 7 live rows x 12 cols

#pragma unroll
    for (int j = 0; j < 7; ++j) {
        const float* sp = &sm[(R + j) * SP + C];
        w[j][0] = *(const float4*)(sp);
        w[j][1] = *(const float4*)(sp + 4);
        w[j][2] = *(const float4*)(sp + 8);
    }

#pragma unroll
    for (int rr = 0; rr < 4; ++rr) {
        float r[4];
#pragma unroll
        for (int cc = 0; cc < 4; ++cc) {
            const int ccol = cc + 3;
            const float center = elem(w[(rr + 3) % 7][ccol >> 2], ccol & 3);
            const float hi = center + 20.0f;
            const float lo = center - 20.0f;
            unsigned dark = 0u, bright = 0u;
#pragma unroll
            for (int k = 0; k < 16; ++k) {
                const int wi = (rr + 3 + DY[k]) % 7;      // static after unroll
                const int col = cc + 3 + DX[k];
                const float t = elem(w[wi][col >> 2], col & 3);
                dark   = (dark << 1)   | (t >= hi ? 1u : 0u);
                bright = (bright << 1) | (t <= lo ? 1u : 0u);
            }
            r[cc] = (det9(dark) | det9(bright)) ? 1.0f : 0.0f;
        }
        const int gy = y0 + R + rr;
        if (gy < IMG_H) {
            *(float4*)(op + (size_t)gy * IMG_W + (x0 + C)) =
                make_float4(r[0], r[1], r[2], r[3]);
        }
        if (rr < 3) {   // roll: overwrite oldest row with tile row R+rr+7
            const float* sp = &sm[(R + rr + 7) * SP + C];
            w[rr % 7][0] = *(const float4*)(sp);
            w[rr % 7][1] = *(const float4*)(sp + 4);
            w[rr % 7][2] = *(const float4*)(sp + 8);
        }
    }
}

extern "C" void kernel_launch(void* const* d_in, const int* in_sizes, int n_in,
                              void* d_out, int out_size, void* d_ws, size_t ws_size,
                              hipStream_t stream) {
    const float* img = (const float*)d_in[0];
    float* out = (float*)d_out;
    const int n_img = in_sizes[0] / (IMG_H * IMG_W);   // = 4
    dim3 grid((IMG_W + TILE_W - 1) / TILE_W,           // 15
              (IMG_H + TILE_H - 1) / TILE_H,           // 34
              n_img);
    fast_score_kernel<<<grid, 256, 0, stream>>>(img, out);
}